// Round 7
// baseline (8434.388 us; speedup 1.0000x reference)
//
#include <hip/hip_runtime.h>
#include <cstdint>
#include <cstddef>

#define NBLK 256
#define NTHR 512
#define B_ 64
#define P_ 196
#define E_ 512
#define A_ 512
#define D_ 512
#define M_ 512
#define V_ 1000
#define L_ 257
#define T_ 256

#define OUT_PRED  0
#define OUT_CAPS  (B_*T_*V_)                 /* 16,384,000 */
#define OUT_ALPHA (OUT_CAPS + B_*L_)         /* 16,400,448 */
#define OUT_SORT  (OUT_ALPHA + B_*T_*P_)     /* 19,611,712 */

typedef _Float16 h2 __attribute__((ext_vector_type(2)));
typedef _Float16 f16x8 __attribute__((ext_vector_type(8)));
typedef float f32x4 __attribute__((ext_vector_type(4)));

struct KP {
  const float* enc; const int* caps; const int* clen;
  const float* emb;
  const float* eaw; const float* eab;
  const float* daw; const float* dab;
  const float* faw; const float* fab;
  const float* wih; const float* bih;
  const float* whh; const float* bhh;
  const float* ihw; const float* ihb;
  const float* icw; const float* icb;
  const float* fbw; const float* fbb;
  const float* fcw; const float* fcb;
  float* out;
  int* bar; int* flb; int* gf;
  int* sort_ind; int* dec_len;
  float* mnT;
  unsigned* hfA; unsigned* hfB; unsigned* hfN;   // f16x2-packed h(t) dbuf / h_new
  float* a2G; float* gateG; float* aweQ; float* sA; float* att1;
};

__device__ __forceinline__ float sigf(float x){ return 1.f/(1.f+__expf(-x)); }
__device__ __forceinline__ float tanhf_(float x){
  float ax = fabsf(x);
  float e = __expf(-2.f*ax);
  float r = (1.f-e)/(1.f+e);
  return x < 0.f ? -r : r;
}
__device__ __forceinline__ unsigned short f2bf(float x){
  unsigned u = __float_as_uint(x);
  unsigned r = (u + 0x7fffu + ((u >> 16) & 1u)) >> 16;   // RNE
  return (unsigned short)r;
}
__device__ __forceinline__ float fdot2f(h2 a, h2 b, float c){
#if __has_builtin(__builtin_amdgcn_fdot2)
  return __builtin_amdgcn_fdot2(a, b, c, false);
#else
  return c + (float)a.x*(float)b.x + (float)a.y*(float)b.y;
#endif
}
__device__ __forceinline__ unsigned packh2(float a, float b){
  h2 v; v.x = (_Float16)a; v.y = (_Float16)b;
  return __builtin_bit_cast(unsigned, v);
}
__device__ __forceinline__ h2 ash2(unsigned u){ return __builtin_bit_cast(h2, u); }
__device__ __forceinline__ f16x8 asf8(uint4 u){ return __builtin_bit_cast(f16x8, u); }

#define LD_A(p)     __hip_atomic_load((p), __ATOMIC_RELAXED, __HIP_MEMORY_SCOPE_AGENT)
#define ST_A(p,v)   __hip_atomic_store((p),(v), __ATOMIC_RELAXED, __HIP_MEMORY_SCOPE_AGENT)
#define ST_REL(p,v) __hip_atomic_store((p),(v), __ATOMIC_RELEASE, __HIP_MEMORY_SCOPE_AGENT)
#define FAA(p)      __hip_atomic_fetch_add((p),1, __ATOMIC_RELAXED, __HIP_MEMORY_SCOPE_AGENT)
__device__ __forceinline__ float ldg_c(const float* p){
  return __hip_atomic_load(p, __ATOMIC_RELAXED, __HIP_MEMORY_SCOPE_AGENT);
}
__device__ __forceinline__ float2 ldg2_c(const float* p){
  unsigned long long u = __hip_atomic_load((const unsigned long long*)p,
                       __ATOMIC_RELAXED, __HIP_MEMORY_SCOPE_AGENT);
  return __builtin_bit_cast(float2, u);
}
__device__ __forceinline__ uint2 ldgu2_c(const unsigned* p){
  unsigned long long u = __hip_atomic_load((const unsigned long long*)p,
                       __ATOMIC_RELAXED, __HIP_MEMORY_SCOPE_AGENT);
  return __builtin_bit_cast(uint2, u);
}
__device__ __forceinline__ void stg_c(float* p, float v){
  __hip_atomic_store(p, v, __ATOMIC_RELAXED, __HIP_MEMORY_SCOPE_AGENT);
}
__device__ __forceinline__ void stgu_c(unsigned* p, unsigned v){
  __hip_atomic_store(p, v, __ATOMIC_RELAXED, __HIP_MEMORY_SCOPE_AGENT);
}
__device__ __forceinline__ void stg2_c(float* p, float a, float b){
  float2 v; v.x = a; v.y = b;
  __hip_atomic_store((unsigned long long*)p,
                     __builtin_bit_cast(unsigned long long, v),
                     __ATOMIC_RELAXED, __HIP_MEMORY_SCOPE_AGENT);
}

// Fenced grid barrier -- pre-phase only (global, 3 uses).
__device__ __forceinline__ void gridbar(int* bar, int blk){
  __syncthreads();
  if (threadIdx.x == 0){
    __builtin_amdgcn_fence(__ATOMIC_RELEASE, "agent");
    int s = LD_A(&bar[144]);
    int* leaf = &bar[(blk & 7)*16];
    if (FAA(leaf) == 31){
      ST_A(leaf, 0);
      if (FAA(&bar[128]) == 7){
        ST_A(&bar[128], 0);
        ST_REL(&bar[144], s+1);
      }
    }
    while (LD_A(&bar[144]) == s) __builtin_amdgcn_s_sleep(2);
    __builtin_amdgcn_fence(__ATOMIC_ACQUIRE, "agent");
  }
  __syncthreads();
}

// Octet-scoped flat flag barrier: each block release-stores its monotonic
// epoch to its own flag (preceding __syncthreads drains vmcnt so all
// sc-scoped stores are LLC-visible first); 32 lanes poll the 32 flags.
__device__ __forceinline__ void octbar(int* fl, int O, int r, int ep){
  __syncthreads();
  if (threadIdx.x == 0) ST_A(&fl[O*64 + r], ep);
  if (threadIdx.x < 32){
    while (LD_A(&fl[O*64 + (int)threadIdx.x]) < ep) __builtin_amdgcn_s_sleep(1);
  }
  asm volatile("" ::: "memory");
  __syncthreads();
}

// ---------------- MFMA K-split GEMV, register-resident weights ----------------
// D[64 cols][8 batches] via 4 M-tiles of mfma_f32_16x16x32_f16; A frags in
// VGPRs (static-indexed); K split 8 ways across waves; partials reduced
// through redW f32[8][512] (slot = col*8 + batch).
#define REDW_STORE() do { \
  const int j = lane & 15; \
  if (j < 8){ \
    const int ib = (lane >> 4) * 4; \
    _Pragma("unroll") \
    for (int r = 0; r < 4; r++){ \
      redW[wave*512 + (( 0 + ib + r)*8) + j] = d0[r]; \
      redW[wave*512 + ((16 + ib + r)*8) + j] = d1[r]; \
      redW[wave*512 + ((32 + ib + r)*8) + j] = d2[r]; \
      redW[wave*512 + ((48 + ib + r)*8) + j] = d3[r]; \
    } \
  } \
} while(0)

// B from LDS chunk-major f16 [K/8][8] (P3 gates GEMM)
template<int KSW>
__device__ __forceinline__ void gemv_regs(const uint4 (&wfr)[4][KSW],
                                          const uint4* __restrict__ x4,
                                          float* redW, int lane, int wave){
  f32x4 d0 = {0.f,0.f,0.f,0.f}, d1 = d0, d2 = d0, d3 = d0;
  const int rowc = lane & 7;
  const int lg = lane >> 4;
  #pragma unroll
  for (int ks = 0; ks < KSW; ks++){
    const int ksg = wave*KSW + ks;
    f16x8 bf = asf8(x4[(ksg*4 + lg)*8 + rowc]);
    d0 = __builtin_amdgcn_mfma_f32_16x16x32_f16(asf8(wfr[0][ks]), bf, d0, 0, 0, 0);
    d1 = __builtin_amdgcn_mfma_f32_16x16x32_f16(asf8(wfr[1][ks]), bf, d1, 0, 0, 0);
    d2 = __builtin_amdgcn_mfma_f32_16x16x32_f16(asf8(wfr[2][ks]), bf, d2, 0, 0, 0);
    d3 = __builtin_amdgcn_mfma_f32_16x16x32_f16(asf8(wfr[3][ks]), bf, d3, 0, 0, 0);
  }
  REDW_STORE();
}

// B loaded DIRECTLY from the f16-packed h array (P1 / final preds).
__device__ __forceinline__ void gemv_dir2(const uint4 (&wfr)[4][2],
                                          const unsigned* __restrict__ hsrc,
                                          float* redW, int lane, int wave){
  f32x4 d0 = {0.f,0.f,0.f,0.f}, d1 = d0, d2 = d0, d3 = d0;
  const int rowc = lane & 7;
  const int lg = lane >> 4;
  #pragma unroll
  for (int ks = 0; ks < 2; ks++){
    const int ksg = wave*2 + ks;
    const unsigned* ad = hsrc + (rowc << 8) + ((ksg*4 + lg) << 2);
    uint2 u0 = ldgu2_c(ad), u1 = ldgu2_c(ad + 2);
    uint4 br; br.x = u0.x; br.y = u0.y; br.z = u1.x; br.w = u1.y;
    f16x8 bf = asf8(br);
    d0 = __builtin_amdgcn_mfma_f32_16x16x32_f16(asf8(wfr[0][ks]), bf, d0, 0, 0, 0);
    d1 = __builtin_amdgcn_mfma_f32_16x16x32_f16(asf8(wfr[1][ks]), bf, d1, 0, 0, 0);
    d2 = __builtin_amdgcn_mfma_f32_16x16x32_f16(asf8(wfr[2][ks]), bf, d2, 0, 0, 0);
    d3 = __builtin_amdgcn_mfma_f32_16x16x32_f16(asf8(wfr[3][ks]), bf, d3, 0, 0, 0);
  }
  REDW_STORE();
}

// LDS map (145.1 KB):
//   [0,      50176) att1L  bf16[49][512]  resident (P2: b=blk>>2,q=blk&3)
//   [50176, 105472) encT2  h2[512][27]    resident
//   [105472,107520) fwL    f32[512]       resident
//   [107520,107584) sbL    int[16]        octet sort_ind + dec_len
//   [107584,   ...) SCRATCH (phase-local, aliased):
//     GEMM: xH8 uint4 (P3: 24KB) at +0; redW f32[8][512] at +24576
//     P2: eL f32[49] at +0; alpha2L u32[25] at +256
//   LSTM state (c, masked h) lives in thread-private REGISTERS of the owning
//   thread (tid = 32*jl + bb2 -- fixed across steps).
__global__ __launch_bounds__(NTHR, 2) void dec_kernel(KP p){
  __shared__ __align__(16) char smem_raw[148544];
  unsigned short* att1L = (unsigned short*)smem_raw;
  unsigned* encT2  = (unsigned*)(smem_raw + 50176);
  float* fwL       = (float*)(smem_raw + 105472);
  int*   sbL       = (int*)(smem_raw + 107520);
  char* SCR        = smem_raw + 107584;
  uint4* xH8_4     = (uint4*)SCR;
  float* redW      = (float*)(SCR + 24576);
  float* eL        = (float*)SCR;                    // P2
  unsigned* alpha2L= (unsigned*)(SCR + 256);

  const int blk  = blockIdx.x;
  const int tid  = threadIdx.x;
  const int lane = tid & 63;
  const int wave = tid >> 6;
  // P2 identity
  const int b    = blk >> 2;
  const int q    = blk & 3;
  // P1/P3 identity: column-tile x batch-octet
  const int ct   = blk & 31;          // 0..31  (also octet rank)
  const int bt   = blk >> 5;          // 0..7   (also octet id)

  // ---------------- Pre0: stable descending argsort + caps gather ----------------
  if (blk == 0){
    if (tid < B_){
      int lb = p.clen[tid];
      int rank = 0;
      for (int j = 0; j < B_; j++){
        int lj = p.clen[j];
        rank += (lj > lb) || (lj == lb && j < tid);
      }
      p.sort_ind[rank] = tid;
      p.dec_len[rank]  = lb - 1;
      p.out[OUT_SORT + rank] = (float)tid;
    }
    __syncthreads();
    for (int idx = tid; idx < B_*L_; idx += NTHR){
      int bb = idx / L_;
      int l = idx - bb*L_;
      int sbv = p.sort_ind[bb];
      p.out[OUT_CAPS + idx] = (float)p.caps[sbv*L_ + l];
    }
  }
  gridbar(p.bar, blk);

  const int sb  = p.sort_ind[b];
  const int dlb = p.dec_len[b];

  // ---------------- Pre1: att1 = enc_s @ enc_att_w^T + b (196 tiles) + mean (64) ----------------
  for (int task = blk; task < 260; task += NBLK){
    if (task < 196){
      const int r0 = task*64;
      float* wL = (float*)smem_raw;             // [512][33]
      float* eLt = (float*)smem_raw + 512*33;   // [64][33]
      const int tx = tid & 31, ty = tid >> 5;   // ty<16
      float acc[4][16];
      #pragma unroll
      for (int i=0;i<4;i++)
        #pragma unroll
        for (int j=0;j<16;j++) acc[i][j] = 0.f;
      for (int k0 = 0; k0 < 512; k0 += 32){
        __syncthreads();
        for (int i = tid; i < 512*32; i += NTHR){
          int a = i >> 5, kk = i & 31;
          wL[a*33 + kk] = p.eaw[a*512 + k0 + kk];
        }
        for (int i = tid; i < 64*32; i += NTHR){
          int rl = i >> 5, kk = i & 31;
          int r = r0 + rl;
          int bb = r / 196;
          int pp = r - bb*196;
          int sbv = p.sort_ind[bb];
          eLt[rl*33 + kk] = p.enc[((size_t)sbv*196 + pp)*512 + k0 + kk];
        }
        __syncthreads();
        for (int kk = 0; kk < 32; kk++){
          float ev[4];
          #pragma unroll
          for (int ii=0;ii<4;ii++) ev[ii] = eLt[(ty*4+ii)*33 + kk];
          #pragma unroll
          for (int jj=0;jj<16;jj++){
            float wv = wL[(tx + 32*jj)*33 + kk];
            #pragma unroll
            for (int ii=0;ii<4;ii++) acc[ii][jj] = fmaf(ev[ii], wv, acc[ii][jj]);
          }
        }
      }
      #pragma unroll
      for (int jj=0;jj<16;jj++){
        int a = tx + 32*jj;
        float bbv = p.eab[a];
        #pragma unroll
        for (int ii=0;ii<4;ii++){
          int r = r0 + ty*4 + ii;
          p.att1[(size_t)r*512 + a] = acc[ii][jj] + bbv;
        }
      }
      __syncthreads();
    } else {
      int bb = task - 196;
      int sbv = p.sort_ind[bb];
      const float* eb = p.enc + (size_t)sbv*P_*E_;
      for (int e = tid; e < E_; e += NTHR){
        float s = 0.f;
        for (int pp = 0; pp < P_; pp++) s += eb[pp*E_ + e];
        p.mnT[bb*512 + e] = s * (1.f/196.f);
      }
    }
  }
  gridbar(p.bar, blk);

  // ---------------- Pre2: residents + persistent weight frags + h0/c0 ----------------
  // (a) P2 residents
  for (int idx = tid; idx < 49*512; idx += NTHR){
    int pp = idx >> 9, a = idx & 511;
    att1L[idx] = f2bf(p.att1[((size_t)(b*196 + q*49 + pp))*512 + a]);
  }
  for (int i = tid; i < 512*25; i += NTHR){
    int p2 = i >> 9, e = i & 511;
    int pr0 = q*49 + 2*p2;
    float e0 = p.enc[((size_t)sb*196 + pr0)*512 + e];
    float e1 = (2*p2+1 < 49) ? p.enc[((size_t)sb*196 + pr0 + 1)*512 + e] : 0.f;
    encT2[e*27 + p2] = packh2(e0, e1);
  }
  fwL[tid] = p.faw[tid];
  if (tid < 8)       sbL[tid]     = p.sort_ind[bt*8 + tid];
  else if (tid < 16) sbL[tid]     = p.dec_len[bt*8 + (tid-8)];
  // (b) persistent register fragments (loaded ONCE, live across the loop).
  uint4 wa[4][2];
  uint4 wg[4][6];
  {
    const int cgb = ct*64 + (lane & 15);
    const int kof = (lane >> 4) << 3;
    #pragma unroll
    for (int mt = 0; mt < 4; mt++){
      int cg = cgb + mt*16;
      #pragma unroll
      for (int ks = 0; ks < 2; ks++){
        int k = (wave*2 + ks)*32 + kof;
        uint4 o = {0u,0u,0u,0u};
        const float* src = nullptr;
        if (cg < 512)        src = p.daw + (size_t)cg*512 + k;
        else if (cg < 1024)  src = p.fbw + (size_t)(cg-512)*512 + k;
        else if (cg < 2024)  src = p.fcw + (size_t)(cg-1024)*512 + k;
        if (src){
          const float4* s4 = (const float4*)src;
          float4 f0 = s4[0], f1 = s4[1];
          o.x = packh2(f0.x,f0.y); o.y = packh2(f0.z,f0.w);
          o.z = packh2(f1.x,f1.y); o.w = packh2(f1.z,f1.w);
        }
        wa[mt][ks] = o;
      }
      int jj = cg >> 2, g = cg & 3;
      #pragma unroll
      for (int ks = 0; ks < 6; ks++){
        int k = (wave*6 + ks)*32 + kof;
        const float* src = (k < 1024) ? p.wih + (size_t)(g*512+jj)*1024 + k
                                      : p.whh + (size_t)(g*512+jj)*512 + (k-1024);
        const float4* s4 = (const float4*)src;
        float4 f0 = s4[0], f1 = s4[1];
        uint4 o;
        o.x = packh2(f0.x,f0.y); o.y = packh2(f0.z,f0.w);
        o.z = packh2(f1.x,f1.y); o.w = packh2(f1.z,f1.w);
        wg[mt][ks] = o;
      }
    }
  }
  // (c) h0/c0 in LSTM-thread registers (tid = 32*jl + bb2) + packed hfA.
  //     LSTM biases (bih+bhh) hoisted to registers too.
  float hreg = 0.f, creg = 0.f;
  float lb0 = 0.f, lb1 = 0.f, lb2 = 0.f, lb3 = 0.f;
  const bool isLstm = (tid & 31) < 8;
  if (isLstm){
    int jl = tid >> 5, bb2 = tid & 7;
    int b8 = bt*8 + bb2, jg = ct*16 + jl;
    const float* mrow = p.mnT + b8*512;
    const float* hw = p.ihw + (size_t)jg*512;
    const float* cw = p.icw + (size_t)jg*512;
    float ah = 0.f, ac = 0.f;
    for (int k = 0; k < 512; k++){ ah = fmaf(hw[k], mrow[k], ah); ac = fmaf(cw[k], mrow[k], ac); }
    hreg = ah + p.ihb[jg];
    creg = ac + p.icb[jg];
    lb0 = p.bih[jg]        + p.bhh[jg];
    lb1 = p.bih[512 + jg]  + p.bhh[512 + jg];
    lb2 = p.bih[1024 + jg] + p.bhh[1024 + jg];
    lb3 = p.bih[1536 + jg] + p.bhh[1536 + jg];
  }
  {
    float h1 = __shfl(hreg, lane + 32);
    if (lane < 8)
      stgu_c(&p.hfA[(bt*8 + lane)*256 + ct*8 + wave], packh2(hreg, h1));
  }
  // P1 output bias: per-thread constant
  float p1b = 0.f;
  {
    int c_local = tid >> 3;
    if (ct < 16){
      int vcl = ct*64 + c_local;
      p1b = (vcl < 512) ? p.dab[vcl] : p.fbb[vcl - 512];
    } else {
      int v2i = (ct-16)*64 + c_local;
      p1b = (v2i < 1000) ? p.fcb[v2i] : 0.f;
    }
  }
  gridbar(p.bar, blk);

  const float fab0 = p.fab[0];
  int ep = 0;

  // ---------------- time loop ----------------
  for (int t = 0; t < T_; t++){
    const unsigned* hfR = (t & 1) ? p.hfB : p.hfA;   // h(t), f16-packed
    unsigned*       hfW = (t & 1) ? p.hfA : p.hfB;   // h(t+1)

    // emb prefetch for P3 (const inputs; latency hides under P1+P2)
    uint4 embPre;
    {
      int cc = tid >> 3, r = tid & 7;
      int cap = p.caps[sbL[r]*L_ + t];
      const float4* er = (const float4*)(p.emb + (size_t)cap*M_ + cc*8);
      float4 f0 = er[0], f1 = er[1];
      embPre.x = packh2(f0.x,f0.y); embPre.y = packh2(f0.z,f0.w);
      embPre.z = packh2(f1.x,f1.y); embPre.w = packh2(f1.z,f1.w);
    }

    // ======== P1: a2+gate (ct<16) | preds(t-1) (ct>=16) -- direct-B MFMA ========
    if (ct < 16 || t > 0){
      const unsigned* xsrc = ((ct < 16) ? hfR : p.hfN) + bt*8*256;
      gemv_dir2(wa, xsrc, redW, lane, wave);
      __syncthreads();
      {
        float s = 0.f;
        #pragma unroll
        for (int w8 = 0; w8 < 8; w8++) s += redW[w8*512 + tid];
        int c_local = tid >> 3, j = tid & 7, b8 = bt*8 + j;
        if (ct < 16){
          int vcl = ct*64 + c_local;
          if (vcl < 512) stg_c(&p.a2G[b8*512 + vcl], s + p1b);
          else           stg_c(&p.gateG[b8*512 + (vcl-512)], sigf(s + p1b));
        } else {
          int v2i = (ct-16)*64 + c_local;
          if (v2i < 1000){
            bool mm = (t-1) < sbL[8 + j];
            p.out[OUT_PRED + ((size_t)b8*T_ + (t-1))*V_ + v2i] = mm ? (s + p1b) : 0.f;
          }
        }
      }
    }
    octbar(p.flb, bt, ct, ++ep);   // B1

    // ======== P2: attention (de-staged; group-sync hidden behind awe) ========
    float l_ex = 0.f, l_mx = -1e30f;   // wave0-only meaningful
    {
      // direct per-lane coherent loads (replaces LDS stage + sync)
      const float* a2p = p.a2G + b*512 + lane*8;
      float2 aA0 = ldg2_c(a2p),     aA1 = ldg2_c(a2p + 2);
      float2 aB0 = ldg2_c(a2p + 4), aB1 = ldg2_c(a2p + 6);
      float gate_r = ldg_c(&p.gateG[b*512 + tid]);
      float4 fA = ((float4*)fwL)[lane*2], fB = ((float4*)fwL)[lane*2+1];
      for (int pp = wave; pp < 49; pp += 8){
        uint4 raw = ((const uint4*)att1L)[pp*64 + lane];
        float s =
          fmaxf(__uint_as_float(raw.x << 16)        + aA0.x, 0.f)*fA.x +
          fmaxf(__uint_as_float(raw.x & 0xffff0000u)+ aA0.y, 0.f)*fA.y +
          fmaxf(__uint_as_float(raw.y << 16)        + aA1.x, 0.f)*fA.z +
          fmaxf(__uint_as_float(raw.y & 0xffff0000u)+ aA1.y, 0.f)*fA.w +
          fmaxf(__uint_as_float(raw.z << 16)        + aB0.x, 0.f)*fB.x +
          fmaxf(__uint_as_float(raw.z & 0xffff0000u)+ aB0.y, 0.f)*fB.y +
          fmaxf(__uint_as_float(raw.w << 16)        + aB1.x, 0.f)*fB.z +
          fmaxf(__uint_as_float(raw.w & 0xffff0000u)+ aB1.y, 0.f)*fB.w;
        #pragma unroll
        for (int o = 32; o > 0; o >>= 1) s += __shfl_down(s, o);
        if (lane == 0) eL[pp] = s + fab0;
      }
      __syncthreads();                              // eL ready
      // wave0: local stats + register-shfl alpha2L pack + release-publish
      if (wave == 0){
        float ev = (lane < 49) ? eL[lane] : -1e30f;
        l_mx = ev;
        #pragma unroll
        for (int o = 32; o > 0; o >>= 1) l_mx = fmaxf(l_mx, __shfl_xor(l_mx, o));
        l_ex = (lane < 49) ? __expf(ev - l_mx) : 0.f;
        float a0 = __shfl(l_ex, 2*lane);
        float a1 = __shfl(l_ex, 2*lane + 1);
        if (lane < 25) alpha2L[lane] = packh2(a0, a1);
        float sum = l_ex;
        #pragma unroll
        for (int o = 32; o > 0; o >>= 1) sum += __shfl_xor(sum, o);
        if (lane == 0){
          stg2_c(&p.sA[(b*4 + q)*2], l_mx, sum);
          ST_REL(&p.gf[b*16 + q], t+1);             // release orders sA before flag
        }
      }
      __syncthreads();                              // alpha2L ready
      // awe~ (unnormalized, local alphas) -- hides the group-sync RTT
      float s = 0.f;
      {
        const unsigned* ec = encT2 + tid*27;
        #pragma unroll 5
        for (int p2 = 0; p2 < 25; p2++)
          s = fdot2f(ash2(ec[p2]), ash2(alpha2L[p2]), s);
      }
      // all-thread poll of the 4 q-flags (no post-poll __syncthreads needed)
      {
        const unsigned long long* g0 = (const unsigned long long*)&p.gf[b*16];
        int tt = t + 1;
        while (true){
          unsigned long long v0 = __hip_atomic_load(g0,     __ATOMIC_RELAXED, __HIP_MEMORY_SCOPE_AGENT);
          unsigned long long v1 = __hip_atomic_load(g0 + 1, __ATOMIC_RELAXED, __HIP_MEMORY_SCOPE_AGENT);
          int m0 = (int)(unsigned)v0, m1 = (int)(v0 >> 32);
          int m2 = (int)(unsigned)v1, m3 = (int)(v1 >> 32);
          if (m0 >= tt && m1 >= tt && m2 >= tt && m3 >= tt) break;
          __builtin_amdgcn_s_sleep(1);
        }
        __builtin_amdgcn_fence(__ATOMIC_ACQUIRE, "agent");
      }
      // per-thread redundant merge: r = exp(mx_q - gmx)/gsum
      float r;
      {
        float2 s0 = ldg2_c(&p.sA[(b*4 + 0)*2]);
        float2 s1 = ldg2_c(&p.sA[(b*4 + 1)*2]);
        float2 s2 = ldg2_c(&p.sA[(b*4 + 2)*2]);
        float2 s3 = ldg2_c(&p.sA[(b*4 + 3)*2]);
        float gmx = fmaxf(fmaxf(s0.x, s1.x), fmaxf(s2.x, s3.x));
        float gsum = s0.y*__expf(s0.x - gmx) + s1.y*__expf(s1.x - gmx)
                   + s2.y*__expf(s2.x - gmx) + s3.y*__expf(s3.x - gmx);
        float mq = (q == 0) ? s0.x : (q == 1) ? s1.x : (q == 2) ? s2.x : s3.x;
        r = __expf(mq - gmx) / gsum;
      }
      stg_c(&p.aweQ[((size_t)b*4 + q)*512 + tid], gate_r * s * r);
      if (wave == 0 && lane < 49)
        p.out[OUT_ALPHA + ((size_t)b*T_ + t)*P_ + q*49 + lane] = (t < dlb) ? l_ex*r : 0.f;
    }
    octbar(p.flb, bt, ct, ++ep);   // B2

    // ======== P3: gates GEMM (MFMA, K=1536) + register LSTM ========
    {
      {
        int cc = tid >> 3, r8 = tid & 7;
        int b8 = bt*8 + r8;
        // emb (prefetched)
        xH8_4[tid] = embPre;
        // h(t) f16
        const unsigned* hs = hfR + b8*256 + cc*4;
        uint2 u0 = ldgu2_c(hs), u1 = ldgu2_c(hs + 2);
        uint4 o; o.x = u0.x; o.y = u0.y; o.z = u1.x; o.w = u1.y;
        xH8_4[1024 + tid] = o;
        // gated awe = plain sum of 4 normalized q-partials
        const float* aw = p.aweQ + (size_t)b8*4*512 + cc*8;
        float a8[8];
        #pragma unroll
        for (int e = 0; e < 8; e += 2){
          float2 q0 = ldg2_c(aw + 0*512 + e);
          float2 q1 = ldg2_c(aw + 1*512 + e);
          float2 q2 = ldg2_c(aw + 2*512 + e);
          float2 q3 = ldg2_c(aw + 3*512 + e);
          a8[e]   = (q0.x + q1.x) + (q2.x + q3.x);
          a8[e+1] = (q0.y + q1.y) + (q2.y + q3.y);
        }
        uint4 ow;
        ow.x = packh2(a8[0],a8[1]); ow.y = packh2(a8[2],a8[3]);
        ow.z = packh2(a8[4],a8[5]); ow.w = packh2(a8[6],a8[7]);
        xH8_4[512 + tid] = ow;
      }
      __syncthreads();
      gemv_regs<6>(wg, xH8_4, redW, lane, wave);
      __syncthreads();
      // reduce 8 wave partials; gates gathered via same-wave shfl
      float s = 0.f;
      #pragma unroll
      for (int w8 = 0; w8 < 8; w8++) s += redW[w8*512 + tid];
      float g1 = __shfl(s, lane + 8);
      float g2 = __shfl(s, lane + 16);
      float g3 = __shfl(s, lane + 24);
      float hnv = 0.f;
      if (isLstm){
        int bb2 = tid & 7;
        float G0 = s  + lb0, G1 = g1 + lb1, G2 = g2 + lb2, G3 = g3 + lb3;
        float i_s = sigf(G0), f_s = sigf(G1), g_t = tanhf_(G2), o_s = sigf(G3);
        float c_new = f_s*creg + i_s*g_t;
        hnv = o_s*tanhf_(c_new);
        bool m = t < sbL[8 + bb2];
        creg = m ? c_new : creg;
        hreg = m ? hnv  : hreg;
      }
      // pack pairs (jl=2w, 2w+1) via lane/lane+32 shfl; store by lane<8
      float hm1 = __shfl(hreg, lane + 32);
      float hn1 = __shfl(hnv,  lane + 32);
      if (lane < 8){
        int b8 = bt*8 + lane;
        stgu_c(&hfW[b8*256 + ct*8 + wave],    packh2(hreg, hm1));
        stgu_c(&p.hfN[b8*256 + ct*8 + wave],  packh2(hnv,  hn1));
      }
    }
    octbar(p.flb, bt, ct, ++ep);   // B0 (h(t+1), hn(t) published)
  }

  // ---- final preds for t = T-1 (direct-B from hfN) ----
  if (ct >= 16){
    gemv_dir2(wa, p.hfN + bt*8*256, redW, lane, wave);
    __syncthreads();
    {
      float s = 0.f;
      #pragma unroll
      for (int w8 = 0; w8 < 8; w8++) s += redW[w8*512 + tid];
      int c_local = tid >> 3, j = tid & 7, b8 = bt*8 + j;
      int v2i = (ct-16)*64 + c_local;
      if (v2i < 1000){
        bool mm = (T_-1) < sbL[8 + j];
        p.out[OUT_PRED + ((size_t)b8*T_ + (T_-1))*V_ + v2i] = mm ? (s + p1b) : 0.f;
      }
    }
  }
}

extern "C" void kernel_launch(void* const* d_in, const int* in_sizes, int n_in,
                              void* d_out, int out_size, void* d_ws, size_t ws_size,
                              hipStream_t stream){
  (void)in_sizes; (void)n_in; (void)out_size; (void)ws_size;
  KP p;
  p.enc  = (const float*)d_in[0];
  p.caps = (const int*)  d_in[1];
  p.clen = (const int*)  d_in[2];
  p.emb  = (const float*)d_in[3];
  p.eaw  = (const float*)d_in[4];  p.eab = (const float*)d_in[5];
  p.daw  = (const float*)d_in[6];  p.dab = (const float*)d_in[7];
  p.faw  = (const float*)d_in[8];  p.fab = (const float*)d_in[9];
  p.wih  = (const float*)d_in[10]; p.bih = (const float*)d_in[11];
  p.whh  = (const float*)d_in[12]; p.bhh = (const float*)d_in[13];
  p.ihw  = (const float*)d_in[14]; p.ihb = (const float*)d_in[15];
  p.icw  = (const float*)d_in[16]; p.icb = (const float*)d_in[17];
  p.fbw  = (const float*)d_in[18]; p.fbb = (const float*)d_in[19];
  p.fcw  = (const float*)d_in[20]; p.fcb = (const float*)d_in[21];
  p.out  = (float*)d_out;

  char* ws = (char*)d_ws;
  size_t off = 0;
  p.bar = (int*)(ws + off); off += 1024;     // fenced pre-barrier (global)
  p.flb = (int*)(ws + off); off += 8*64*4;   // octet flag barrier
  p.gf  = (int*)(ws + off); off += 64*16*4;  // per-b group flags (stats sync)
  size_t zero_bytes = off;
  p.sort_ind = (int*)(ws + off); off += 64*4;
  p.dec_len  = (int*)(ws + off); off += 64*4;
  off = (off + 255) & ~(size_t)255;
  p.mnT   = (float*)(ws + off); off += (size_t)B_*512*4;
  p.hfA   = (unsigned*)(ws + off); off += (size_t)B_*256*4;
  p.hfB   = (unsigned*)(ws + off); off += (size_t)B_*256*4;
  p.hfN   = (unsigned*)(ws + off); off += (size_t)B_*256*4;
  p.a2G   = (float*)(ws + off); off += (size_t)B_*512*4;
  p.gateG = (float*)(ws + off); off += (size_t)B_*512*4;
  p.aweQ  = (float*)(ws + off); off += (size_t)B_*4*512*4;
  p.sA    = (float*)(ws + off); off += (size_t)B_*4*2*4;
  off = (off + 255) & ~(size_t)255;
  p.att1  = (float*)(ws + off); off += (size_t)B_*P_*A_*4;

  hipMemsetAsync(ws, 0, zero_bytes, stream);

  void* args[] = { (void*)&p };
  hipLaunchCooperativeKernel((const void*)dec_kernel,
                             dim3(NBLK), dim3(NTHR), args, 0, stream);
}

// Round 8
// 4857.004 us; speedup vs baseline: 1.7365x; 1.7365x over previous
//
#include <hip/hip_runtime.h>
#include <cstdint>
#include <cstddef>

#define NBLK 256
#define NTHR 512
#define B_ 64
#define P_ 196
#define E_ 512
#define A_ 512
#define D_ 512
#define M_ 512
#define V_ 1000
#define L_ 257
#define T_ 256

#define OUT_PRED  0
#define OUT_CAPS  (B_*T_*V_)                 /* 16,384,000 */
#define OUT_ALPHA (OUT_CAPS + B_*L_)         /* 16,400,448 */
#define OUT_SORT  (OUT_ALPHA + B_*T_*P_)     /* 19,611,712 */

typedef _Float16 h2 __attribute__((ext_vector_type(2)));
typedef _Float16 f16x8 __attribute__((ext_vector_type(8)));
typedef float f32x4 __attribute__((ext_vector_type(4)));

struct KP {
  const float* enc; const int* caps; const int* clen;
  const float* emb;
  const float* eaw; const float* eab;
  const float* daw; const float* dab;
  const float* faw; const float* fab;
  const float* wih; const float* bih;
  const float* whh; const float* bhh;
  const float* ihw; const float* ihb;
  const float* icw; const float* icb;
  const float* fbw; const float* fbb;
  const float* fcw; const float* fcb;
  float* out;
  int* bar; int* flb; int* gf;
  int* sort_ind; int* dec_len;
  float* mnT;
  unsigned* hfA; unsigned* hfB; unsigned* hfN;   // f16x2-packed h(t) dbuf / h_new
  float* a2G; float* gateG; float* aweQ; float* sA; float* att1;
};

__device__ __forceinline__ float sigf(float x){ return 1.f/(1.f+__expf(-x)); }
__device__ __forceinline__ float tanhf_(float x){
  float ax = fabsf(x);
  float e = __expf(-2.f*ax);
  float r = (1.f-e)/(1.f+e);
  return x < 0.f ? -r : r;
}
__device__ __forceinline__ unsigned short f2bf(float x){
  unsigned u = __float_as_uint(x);
  unsigned r = (u + 0x7fffu + ((u >> 16) & 1u)) >> 16;   // RNE
  return (unsigned short)r;
}
__device__ __forceinline__ float fdot2f(h2 a, h2 b, float c){
#if __has_builtin(__builtin_amdgcn_fdot2)
  return __builtin_amdgcn_fdot2(a, b, c, false);
#else
  return c + (float)a.x*(float)b.x + (float)a.y*(float)b.y;
#endif
}
__device__ __forceinline__ unsigned packh2(float a, float b){
  h2 v; v.x = (_Float16)a; v.y = (_Float16)b;
  return __builtin_bit_cast(unsigned, v);
}
__device__ __forceinline__ h2 ash2(unsigned u){ return __builtin_bit_cast(h2, u); }
__device__ __forceinline__ f16x8 asf8(uint4 u){ return __builtin_bit_cast(f16x8, u); }

#define LD_A(p)     __hip_atomic_load((p), __ATOMIC_RELAXED, __HIP_MEMORY_SCOPE_AGENT)
#define ST_A(p,v)   __hip_atomic_store((p),(v), __ATOMIC_RELAXED, __HIP_MEMORY_SCOPE_AGENT)
#define ST_REL(p,v) __hip_atomic_store((p),(v), __ATOMIC_RELEASE, __HIP_MEMORY_SCOPE_AGENT)
#define FAA(p)      __hip_atomic_fetch_add((p),1, __ATOMIC_RELAXED, __HIP_MEMORY_SCOPE_AGENT)
__device__ __forceinline__ float ldg_c(const float* p){
  return __hip_atomic_load(p, __ATOMIC_RELAXED, __HIP_MEMORY_SCOPE_AGENT);
}
__device__ __forceinline__ float2 ldg2_c(const float* p){
  unsigned long long u = __hip_atomic_load((const unsigned long long*)p,
                       __ATOMIC_RELAXED, __HIP_MEMORY_SCOPE_AGENT);
  return __builtin_bit_cast(float2, u);
}
__device__ __forceinline__ uint2 ldgu2_c(const unsigned* p){
  unsigned long long u = __hip_atomic_load((const unsigned long long*)p,
                       __ATOMIC_RELAXED, __HIP_MEMORY_SCOPE_AGENT);
  return __builtin_bit_cast(uint2, u);
}
__device__ __forceinline__ void stg_c(float* p, float v){
  __hip_atomic_store(p, v, __ATOMIC_RELAXED, __HIP_MEMORY_SCOPE_AGENT);
}
__device__ __forceinline__ void stgu_c(unsigned* p, unsigned v){
  __hip_atomic_store(p, v, __ATOMIC_RELAXED, __HIP_MEMORY_SCOPE_AGENT);
}
__device__ __forceinline__ void stg2_c(float* p, float a, float b){
  float2 v; v.x = a; v.y = b;
  __hip_atomic_store((unsigned long long*)p,
                     __builtin_bit_cast(unsigned long long, v),
                     __ATOMIC_RELAXED, __HIP_MEMORY_SCOPE_AGENT);
}

// Fenced grid barrier -- pre-phase only (global, 3 uses).
__device__ __forceinline__ void gridbar(int* bar, int blk){
  __syncthreads();
  if (threadIdx.x == 0){
    __builtin_amdgcn_fence(__ATOMIC_RELEASE, "agent");
    int s = LD_A(&bar[144]);
    int* leaf = &bar[(blk & 7)*16];
    if (FAA(leaf) == 31){
      ST_A(leaf, 0);
      if (FAA(&bar[128]) == 7){
        ST_A(&bar[128], 0);
        ST_REL(&bar[144], s+1);
      }
    }
    while (LD_A(&bar[144]) == s) __builtin_amdgcn_s_sleep(2);
    __builtin_amdgcn_fence(__ATOMIC_ACQUIRE, "agent");
  }
  __syncthreads();
}

// Octet-scoped flat flag barrier: each block release-stores its monotonic
// epoch to its own flag (preceding __syncthreads drains vmcnt so all
// sc-scoped stores are LLC-visible first); 32 lanes poll the 32 flags.
__device__ __forceinline__ void octbar(int* fl, int O, int r, int ep){
  __syncthreads();
  if (threadIdx.x == 0) ST_A(&fl[O*64 + r], ep);
  if (threadIdx.x < 32){
    while (LD_A(&fl[O*64 + (int)threadIdx.x]) < ep) __builtin_amdgcn_s_sleep(1);
  }
  asm volatile("" ::: "memory");
  __syncthreads();
}

// ---------------- MFMA K-split GEMV, register-resident weights ----------------
// D[64 cols][8 batches] via 4 M-tiles of mfma_f32_16x16x32_f16; A frags in
// VGPRs (static-indexed); K split 8 ways across waves; partials reduced
// through redW f32[8][512] (slot = col*8 + batch).
#define REDW_STORE() do { \
  const int j = lane & 15; \
  if (j < 8){ \
    const int ib = (lane >> 4) * 4; \
    _Pragma("unroll") \
    for (int r = 0; r < 4; r++){ \
      redW[wave*512 + (( 0 + ib + r)*8) + j] = d0[r]; \
      redW[wave*512 + ((16 + ib + r)*8) + j] = d1[r]; \
      redW[wave*512 + ((32 + ib + r)*8) + j] = d2[r]; \
      redW[wave*512 + ((48 + ib + r)*8) + j] = d3[r]; \
    } \
  } \
} while(0)

// B from LDS chunk-major f16 [K/8][8] (P3 gates GEMM)
template<int KSW>
__device__ __forceinline__ void gemv_regs(const uint4 (&wfr)[4][KSW],
                                          const uint4* __restrict__ x4,
                                          float* redW, int lane, int wave){
  f32x4 d0 = {0.f,0.f,0.f,0.f}, d1 = d0, d2 = d0, d3 = d0;
  const int rowc = lane & 7;
  const int lg = lane >> 4;
  #pragma unroll
  for (int ks = 0; ks < KSW; ks++){
    const int ksg = wave*KSW + ks;
    f16x8 bf = asf8(x4[(ksg*4 + lg)*8 + rowc]);
    d0 = __builtin_amdgcn_mfma_f32_16x16x32_f16(asf8(wfr[0][ks]), bf, d0, 0, 0, 0);
    d1 = __builtin_amdgcn_mfma_f32_16x16x32_f16(asf8(wfr[1][ks]), bf, d1, 0, 0, 0);
    d2 = __builtin_amdgcn_mfma_f32_16x16x32_f16(asf8(wfr[2][ks]), bf, d2, 0, 0, 0);
    d3 = __builtin_amdgcn_mfma_f32_16x16x32_f16(asf8(wfr[3][ks]), bf, d3, 0, 0, 0);
  }
  REDW_STORE();
}

// B loaded DIRECTLY from the f16-packed h array (P1 / final preds).
__device__ __forceinline__ void gemv_dir2(const uint4 (&wfr)[4][2],
                                          const unsigned* __restrict__ hsrc,
                                          float* redW, int lane, int wave){
  f32x4 d0 = {0.f,0.f,0.f,0.f}, d1 = d0, d2 = d0, d3 = d0;
  const int rowc = lane & 7;
  const int lg = lane >> 4;
  #pragma unroll
  for (int ks = 0; ks < 2; ks++){
    const int ksg = wave*2 + ks;
    const unsigned* ad = hsrc + (rowc << 8) + ((ksg*4 + lg) << 2);
    uint2 u0 = ldgu2_c(ad), u1 = ldgu2_c(ad + 2);
    uint4 br; br.x = u0.x; br.y = u0.y; br.z = u1.x; br.w = u1.y;
    f16x8 bf = asf8(br);
    d0 = __builtin_amdgcn_mfma_f32_16x16x32_f16(asf8(wfr[0][ks]), bf, d0, 0, 0, 0);
    d1 = __builtin_amdgcn_mfma_f32_16x16x32_f16(asf8(wfr[1][ks]), bf, d1, 0, 0, 0);
    d2 = __builtin_amdgcn_mfma_f32_16x16x32_f16(asf8(wfr[2][ks]), bf, d2, 0, 0, 0);
    d3 = __builtin_amdgcn_mfma_f32_16x16x32_f16(asf8(wfr[3][ks]), bf, d3, 0, 0, 0);
  }
  REDW_STORE();
}

// LDS map (145.1 KB):
//   [0,      50176) att1L  bf16[49][512]  resident (P2: b=blk>>2,q=blk&3)
//   [50176, 105472) encT2  h2[512][27]    resident
//   [105472,107520) fwL    f32[512]       resident
//   [107520,107584) sbL    int[16]        octet sort_ind + dec_len
//   [107584,   ...) SCRATCH (phase-local, aliased):
//     GEMM: xH8 uint4 (P3: 24KB) at +0; redW f32[8][512] at +24576
//     P2: a2L[512] gateL[512] eL[64] alphaL[64] alpha2L[32] at +0
//   LSTM state (c, masked h) lives in thread-private REGISTERS of the
//   owning thread (tid = 32*jl + bb2 -- fixed across steps).
__global__ __launch_bounds__(NTHR, 2) void dec_kernel(KP p){
  __shared__ __align__(16) char smem_raw[148544];
  unsigned short* att1L = (unsigned short*)smem_raw;
  unsigned* encT2  = (unsigned*)(smem_raw + 50176);
  float* fwL       = (float*)(smem_raw + 105472);
  int*   sbL       = (int*)(smem_raw + 107520);
  char* SCR        = smem_raw + 107584;
  uint4* xH8_4     = (uint4*)SCR;
  float* redW      = (float*)(SCR + 24576);
  float* a2L       = (float*)SCR;                    // P2
  float* gateL     = (float*)(SCR + 2048);
  float* eL        = (float*)(SCR + 4096);
  float* alphaL    = (float*)(SCR + 4352);
  unsigned* alpha2L= (unsigned*)(SCR + 4608);

  const int blk  = blockIdx.x;
  const int tid  = threadIdx.x;
  const int lane = tid & 63;
  const int wave = tid >> 6;
  // P2 identity
  const int b    = blk >> 2;
  const int q    = blk & 3;
  // P1/P3 identity: column-tile x batch-octet
  const int ct   = blk & 31;          // 0..31  (also octet rank)
  const int bt   = blk >> 5;          // 0..7   (also octet id)

  // ---------------- Pre0: stable descending argsort + caps gather ----------------
  if (blk == 0){
    if (tid < B_){
      int lb = p.clen[tid];
      int rank = 0;
      for (int j = 0; j < B_; j++){
        int lj = p.clen[j];
        rank += (lj > lb) || (lj == lb && j < tid);
      }
      p.sort_ind[rank] = tid;
      p.dec_len[rank]  = lb - 1;
      p.out[OUT_SORT + rank] = (float)tid;
    }
    __syncthreads();
    for (int idx = tid; idx < B_*L_; idx += NTHR){
      int bb = idx / L_;
      int l = idx - bb*L_;
      int sbv = p.sort_ind[bb];
      p.out[OUT_CAPS + idx] = (float)p.caps[sbv*L_ + l];
    }
  }
  gridbar(p.bar, blk);

  const int sb  = p.sort_ind[b];
  const int dlb = p.dec_len[b];

  // ---------------- Pre1: att1 = enc_s @ enc_att_w^T + b (196 tiles) + mean (64) ----------------
  for (int task = blk; task < 260; task += NBLK){
    if (task < 196){
      const int r0 = task*64;
      float* wL = (float*)smem_raw;             // [512][33]
      float* eLt = (float*)smem_raw + 512*33;   // [64][33]
      const int tx = tid & 31, ty = tid >> 5;   // ty<16
      float acc[4][16];
      #pragma unroll
      for (int i=0;i<4;i++)
        #pragma unroll
        for (int j=0;j<16;j++) acc[i][j] = 0.f;
      for (int k0 = 0; k0 < 512; k0 += 32){
        __syncthreads();
        for (int i = tid; i < 512*32; i += NTHR){
          int a = i >> 5, kk = i & 31;
          wL[a*33 + kk] = p.eaw[a*512 + k0 + kk];
        }
        for (int i = tid; i < 64*32; i += NTHR){
          int rl = i >> 5, kk = i & 31;
          int r = r0 + rl;
          int bb = r / 196;
          int pp = r - bb*196;
          int sbv = p.sort_ind[bb];
          eLt[rl*33 + kk] = p.enc[((size_t)sbv*196 + pp)*512 + k0 + kk];
        }
        __syncthreads();
        for (int kk = 0; kk < 32; kk++){
          float ev[4];
          #pragma unroll
          for (int ii=0;ii<4;ii++) ev[ii] = eLt[(ty*4+ii)*33 + kk];
          #pragma unroll
          for (int jj=0;jj<16;jj++){
            float wv = wL[(tx + 32*jj)*33 + kk];
            #pragma unroll
            for (int ii=0;ii<4;ii++) acc[ii][jj] = fmaf(ev[ii], wv, acc[ii][jj]);
          }
        }
      }
      #pragma unroll
      for (int jj=0;jj<16;jj++){
        int a = tx + 32*jj;
        float bbv = p.eab[a];
        #pragma unroll
        for (int ii=0;ii<4;ii++){
          int r = r0 + ty*4 + ii;
          p.att1[(size_t)r*512 + a] = acc[ii][jj] + bbv;
        }
      }
      __syncthreads();
    } else {
      int bb = task - 196;
      int sbv = p.sort_ind[bb];
      const float* eb = p.enc + (size_t)sbv*P_*E_;
      for (int e = tid; e < E_; e += NTHR){
        float s = 0.f;
        for (int pp = 0; pp < P_; pp++) s += eb[pp*E_ + e];
        p.mnT[bb*512 + e] = s * (1.f/196.f);
      }
    }
  }
  gridbar(p.bar, blk);

  // ---------------- Pre2: residents + persistent weight frags + h0/c0 ----------------
  // (a) P2 residents
  for (int idx = tid; idx < 49*512; idx += NTHR){
    int pp = idx >> 9, a = idx & 511;
    att1L[idx] = f2bf(p.att1[((size_t)(b*196 + q*49 + pp))*512 + a]);
  }
  for (int i = tid; i < 512*25; i += NTHR){
    int p2 = i >> 9, e = i & 511;
    int pr0 = q*49 + 2*p2;
    float e0 = p.enc[((size_t)sb*196 + pr0)*512 + e];
    float e1 = (2*p2+1 < 49) ? p.enc[((size_t)sb*196 + pr0 + 1)*512 + e] : 0.f;
    encT2[e*27 + p2] = packh2(e0, e1);
  }
  fwL[tid] = p.faw[tid];
  if (tid < 8)       sbL[tid]     = p.sort_ind[bt*8 + tid];
  else if (tid < 16) sbL[tid]     = p.dec_len[bt*8 + (tid-8)];
  // (b) persistent register fragments (loaded ONCE, live across the loop).
  uint4 wa[4][2];
  uint4 wg[4][6];
  {
    const int cgb = ct*64 + (lane & 15);
    const int kof = (lane >> 4) << 3;
    #pragma unroll
    for (int mt = 0; mt < 4; mt++){
      int cg = cgb + mt*16;
      #pragma unroll
      for (int ks = 0; ks < 2; ks++){
        int k = (wave*2 + ks)*32 + kof;
        uint4 o = {0u,0u,0u,0u};
        const float* src = nullptr;
        if (cg < 512)        src = p.daw + (size_t)cg*512 + k;
        else if (cg < 1024)  src = p.fbw + (size_t)(cg-512)*512 + k;
        else if (cg < 2024)  src = p.fcw + (size_t)(cg-1024)*512 + k;
        if (src){
          const float4* s4 = (const float4*)src;
          float4 f0 = s4[0], f1 = s4[1];
          o.x = packh2(f0.x,f0.y); o.y = packh2(f0.z,f0.w);
          o.z = packh2(f1.x,f1.y); o.w = packh2(f1.z,f1.w);
        }
        wa[mt][ks] = o;
      }
      int jj = cg >> 2, g = cg & 3;
      #pragma unroll
      for (int ks = 0; ks < 6; ks++){
        int k = (wave*6 + ks)*32 + kof;
        const float* src = (k < 1024) ? p.wih + (size_t)(g*512+jj)*1024 + k
                                      : p.whh + (size_t)(g*512+jj)*512 + (k-1024);
        const float4* s4 = (const float4*)src;
        float4 f0 = s4[0], f1 = s4[1];
        uint4 o;
        o.x = packh2(f0.x,f0.y); o.y = packh2(f0.z,f0.w);
        o.z = packh2(f1.x,f1.y); o.w = packh2(f1.z,f1.w);
        wg[mt][ks] = o;
      }
    }
  }
  // (c) h0/c0 in LSTM-thread registers (tid = 32*jl + bb2) + packed hfA.
  //     LSTM biases (bih+bhh) hoisted to registers too.
  float hreg = 0.f, creg = 0.f;
  float lb0 = 0.f, lb1 = 0.f, lb2 = 0.f, lb3 = 0.f;
  const bool isLstm = (tid & 31) < 8;
  if (isLstm){
    int jl = tid >> 5, bb2 = tid & 7;
    int b8 = bt*8 + bb2, jg = ct*16 + jl;
    const float* mrow = p.mnT + b8*512;
    const float* hw = p.ihw + (size_t)jg*512;
    const float* cw = p.icw + (size_t)jg*512;
    float ah = 0.f, ac = 0.f;
    for (int k = 0; k < 512; k++){ ah = fmaf(hw[k], mrow[k], ah); ac = fmaf(cw[k], mrow[k], ac); }
    hreg = ah + p.ihb[jg];
    creg = ac + p.icb[jg];
    lb0 = p.bih[jg]        + p.bhh[jg];
    lb1 = p.bih[512 + jg]  + p.bhh[512 + jg];
    lb2 = p.bih[1024 + jg] + p.bhh[1024 + jg];
    lb3 = p.bih[1536 + jg] + p.bhh[1536 + jg];
  }
  {
    float h1 = __shfl(hreg, lane + 32);
    if (lane < 8)
      stgu_c(&p.hfA[(bt*8 + lane)*256 + ct*8 + wave], packh2(hreg, h1));
  }
  // P1 output bias: per-thread constant
  float p1b = 0.f;
  {
    int c_local = tid >> 3;
    if (ct < 16){
      int vcl = ct*64 + c_local;
      p1b = (vcl < 512) ? p.dab[vcl] : p.fbb[vcl - 512];
    } else {
      int v2i = (ct-16)*64 + c_local;
      p1b = (v2i < 1000) ? p.fcb[v2i] : 0.f;
    }
  }
  gridbar(p.bar, blk);

  const float fab0 = p.fab[0];
  int ep = 0;

  // ---------------- time loop: 3 octet flag barriers + stats-only group sync ----------------
  for (int t = 0; t < T_; t++){
    const unsigned* hfR = (t & 1) ? p.hfB : p.hfA;   // h(t), f16-packed
    unsigned*       hfW = (t & 1) ? p.hfA : p.hfB;   // h(t+1)

    // emb prefetch for P3 (const inputs; latency hides under P1+P2)
    uint4 embPre;
    {
      int cc = tid >> 3, r = tid & 7;
      int cap = p.caps[sbL[r]*L_ + t];
      const float4* er = (const float4*)(p.emb + (size_t)cap*M_ + cc*8);
      float4 f0 = er[0], f1 = er[1];
      embPre.x = packh2(f0.x,f0.y); embPre.y = packh2(f0.z,f0.w);
      embPre.z = packh2(f1.x,f1.y); embPre.w = packh2(f1.z,f1.w);
    }

    // ======== P1: a2+gate (ct<16) | preds(t-1) (ct>=16) -- direct-B MFMA ========
    if (ct < 16 || t > 0){
      const unsigned* xsrc = ((ct < 16) ? hfR : p.hfN) + bt*8*256;
      gemv_dir2(wa, xsrc, redW, lane, wave);
      __syncthreads();
      {
        float s = 0.f;
        #pragma unroll
        for (int w8 = 0; w8 < 8; w8++) s += redW[w8*512 + tid];
        int c_local = tid >> 3, j = tid & 7, b8 = bt*8 + j;
        if (ct < 16){
          int vcl = ct*64 + c_local;
          if (vcl < 512) stg_c(&p.a2G[b8*512 + vcl], s + p1b);
          else           stg_c(&p.gateG[b8*512 + (vcl-512)], sigf(s + p1b));
        } else {
          int v2i = (ct-16)*64 + c_local;
          if (v2i < 1000){
            bool mm = (t-1) < sbL[8 + j];
            p.out[OUT_PRED + ((size_t)b8*T_ + (t-1))*V_ + v2i] = mm ? (s + p1b) : 0.f;
          }
        }
      }
    }
    octbar(p.flb, bt, ct, ++ep);   // B1

    // ======== P2: attention (R6 structure: LDS stage + tid<4 stats sync) ========
    {
      a2L[tid]   = ldg_c(&p.a2G[b*512 + tid]);
      gateL[tid] = ldg_c(&p.gateG[b*512 + tid]);
      __syncthreads();
      // e for own 49 rows from bf16 att1L -> eL
      {
        float4 aA = ((float4*)a2L)[lane*2], aB = ((float4*)a2L)[lane*2+1];
        float4 fA = ((float4*)fwL)[lane*2], fB = ((float4*)fwL)[lane*2+1];
        for (int pp = wave; pp < 49; pp += 8){
          uint4 raw = ((const uint4*)att1L)[pp*64 + lane];
          float s =
            fmaxf(__uint_as_float(raw.x << 16)        + aA.x, 0.f)*fA.x +
            fmaxf(__uint_as_float(raw.x & 0xffff0000u)+ aA.y, 0.f)*fA.y +
            fmaxf(__uint_as_float(raw.y << 16)        + aA.z, 0.f)*fA.z +
            fmaxf(__uint_as_float(raw.y & 0xffff0000u)+ aA.w, 0.f)*fA.w +
            fmaxf(__uint_as_float(raw.z << 16)        + aB.x, 0.f)*fB.x +
            fmaxf(__uint_as_float(raw.z & 0xffff0000u)+ aB.y, 0.f)*fB.y +
            fmaxf(__uint_as_float(raw.w << 16)        + aB.z, 0.f)*fB.z +
            fmaxf(__uint_as_float(raw.w & 0xffff0000u)+ aB.w, 0.f)*fB.w;
          #pragma unroll
          for (int o = 32; o > 0; o >>= 1) s += __shfl_down(s, o);
          if (lane == 0) eL[pp] = s + fab0;
        }
      }
      __syncthreads();
      // wave0: local stats over own 49 -> publish (mx,sum) only
      float l_ex = 0.f, l_mx = -1e30f;
      if (wave == 0){
        float ev = (lane < 49) ? eL[lane] : -1e30f;
        l_mx = ev;
        #pragma unroll
        for (int o = 32; o > 0; o >>= 1) l_mx = fmaxf(l_mx, __shfl_xor(l_mx, o));
        l_ex = (lane < 49) ? __expf(ev - l_mx) : 0.f;
        float sum = l_ex;
        #pragma unroll
        for (int o = 32; o > 0; o >>= 1) sum += __shfl_xor(sum, o);
        if (lane == 0) stg2_c(&p.sA[(b*4 + q)*2], l_mx, sum);
      }
      __syncthreads();                      // drain sA store
      if (tid == 0) ST_A(&p.gf[b*16 + q], t+1);
      if (tid < 4){
        while (LD_A(&p.gf[b*16 + tid]) < t+1) __builtin_amdgcn_s_sleep(1);
      }
      asm volatile("" ::: "memory");
      __syncthreads();
      // wave0: merge global stats, normalize own 49, write alpha out
      if (wave == 0){
        float2 s0 = ldg2_c(&p.sA[(b*4 + 0)*2]);
        float2 s1 = ldg2_c(&p.sA[(b*4 + 1)*2]);
        float2 s2 = ldg2_c(&p.sA[(b*4 + 2)*2]);
        float2 s3 = ldg2_c(&p.sA[(b*4 + 3)*2]);
        float gmx = fmaxf(fmaxf(s0.x, s1.x), fmaxf(s2.x, s3.x));
        float gsum = s0.y*__expf(s0.x - gmx) + s1.y*__expf(s1.x - gmx)
                   + s2.y*__expf(s2.x - gmx) + s3.y*__expf(s3.x - gmx);
        float r = __expf(l_mx - gmx) / gsum;
        if (lane < 49){
          float al = l_ex * r;
          alphaL[lane] = al;
          p.out[OUT_ALPHA + ((size_t)b*T_ + t)*P_ + q*49 + lane] = (t < dlb) ? al : 0.f;
        }
      }
      __syncthreads();
      if (tid < 25){
        float a0 = alphaL[2*tid];
        float a1 = (2*tid+1 < 49) ? alphaL[2*tid + 1] : 0.f;
        alpha2L[tid] = packh2(a0, a1);
      }
      __syncthreads();
      {
        const unsigned* ec = encT2 + tid*27;
        float s = 0.f;
        #pragma unroll 5
        for (int p2 = 0; p2 < 25; p2++)
          s = fdot2f(ash2(ec[p2]), ash2(alpha2L[p2]), s);
        // normalized, gated awe partial -- P3 merge is a plain 4-way sum
        stg_c(&p.aweQ[((size_t)b*4 + q)*512 + tid], gateL[tid]*s);
      }
    }
    octbar(p.flb, bt, ct, ++ep);   // B2

    // ======== P3: gates GEMM (MFMA, K=1536) + register LSTM ========
    {
      {
        int cc = tid >> 3, r8 = tid & 7;
        int b8 = bt*8 + r8;
        // emb (prefetched)
        xH8_4[tid] = embPre;
        // h(t) f16
        const unsigned* hs = hfR + b8*256 + cc*4;
        uint2 u0 = ldgu2_c(hs), u1 = ldgu2_c(hs + 2);
        uint4 o; o.x = u0.x; o.y = u0.y; o.z = u1.x; o.w = u1.y;
        xH8_4[1024 + tid] = o;
        // gated awe = plain sum of 4 normalized q-partials
        const float* aw = p.aweQ + (size_t)b8*4*512 + cc*8;
        float a8[8];
        #pragma unroll
        for (int e = 0; e < 8; e += 2){
          float2 q0 = ldg2_c(aw + 0*512 + e);
          float2 q1 = ldg2_c(aw + 1*512 + e);
          float2 q2 = ldg2_c(aw + 2*512 + e);
          float2 q3 = ldg2_c(aw + 3*512 + e);
          a8[e]   = (q0.x + q1.x) + (q2.x + q3.x);
          a8[e+1] = (q0.y + q1.y) + (q2.y + q3.y);
        }
        uint4 ow;
        ow.x = packh2(a8[0],a8[1]); ow.y = packh2(a8[2],a8[3]);
        ow.z = packh2(a8[4],a8[5]); ow.w = packh2(a8[6],a8[7]);
        xH8_4[512 + tid] = ow;
      }
      __syncthreads();
      gemv_regs<6>(wg, xH8_4, redW, lane, wave);
      __syncthreads();
      // reduce 8 wave partials; gates gathered via same-wave shfl
      float s = 0.f;
      #pragma unroll
      for (int w8 = 0; w8 < 8; w8++) s += redW[w8*512 + tid];
      float g1 = __shfl(s, lane + 8);
      float g2 = __shfl(s, lane + 16);
      float g3 = __shfl(s, lane + 24);
      float hnv = 0.f;
      if (isLstm){
        int bb2 = tid & 7;
        float G0 = s  + lb0, G1 = g1 + lb1, G2 = g2 + lb2, G3 = g3 + lb3;
        float i_s = sigf(G0), f_s = sigf(G1), g_t = tanhf_(G2), o_s = sigf(G3);
        float c_new = f_s*creg + i_s*g_t;
        hnv = o_s*tanhf_(c_new);
        bool m = t < sbL[8 + bb2];
        creg = m ? c_new : creg;
        hreg = m ? hnv  : hreg;
      }
      // pack pairs (jl=2w, 2w+1) via lane/lane+32 shfl; store by lane<8
      float hm1 = __shfl(hreg, lane + 32);
      float hn1 = __shfl(hnv,  lane + 32);
      if (lane < 8){
        int b8 = bt*8 + lane;
        stgu_c(&hfW[b8*256 + ct*8 + wave],    packh2(hreg, hm1));
        stgu_c(&p.hfN[b8*256 + ct*8 + wave],  packh2(hnv,  hn1));
      }
    }
    octbar(p.flb, bt, ct, ++ep);   // B0 (h(t+1), hn(t) published)
  }

  // ---- final preds for t = T-1 (direct-B from hfN) ----
  if (ct >= 16){
    gemv_dir2(wa, p.hfN + bt*8*256, redW, lane, wave);
    __syncthreads();
    {
      float s = 0.f;
      #pragma unroll
      for (int w8 = 0; w8 < 8; w8++) s += redW[w8*512 + tid];
      int c_local = tid >> 3, j = tid & 7, b8 = bt*8 + j;
      int v2i = (ct-16)*64 + c_local;
      if (v2i < 1000){
        bool mm = (T_-1) < sbL[8 + j];
        p.out[OUT_PRED + ((size_t)b8*T_ + (T_-1))*V_ + v2i] = mm ? (s + p1b) : 0.f;
      }
    }
  }
}

extern "C" void kernel_launch(void* const* d_in, const int* in_sizes, int n_in,
                              void* d_out, int out_size, void* d_ws, size_t ws_size,
                              hipStream_t stream){
  (void)in_sizes; (void)n_in; (void)out_size; (void)ws_size;
  KP p;
  p.enc  = (const float*)d_in[0];
  p.caps = (const int*)  d_in[1];
  p.clen = (const int*)  d_in[2];
  p.emb  = (const float*)d_in[3];
  p.eaw  = (const float*)d_in[4];  p.eab = (const float*)d_in[5];
  p.daw  = (const float*)d_in[6];  p.dab = (const float*)d_in[7];
  p.faw  = (const float*)d_in[8];  p.fab = (const float*)d_in[9];
  p.wih  = (const float*)d_in[10]; p.bih = (const float*)d_in[11];
  p.whh  = (const float*)d_in[12]; p.bhh = (const float*)d_in[13];
  p.ihw  = (const float*)d_in[14]; p.ihb = (const float*)d_in[15];
  p.icw  = (const float*)d_in[16]; p.icb = (const float*)d_in[17];
  p.fbw  = (const float*)d_in[18]; p.fbb = (const float*)d_in[19];
  p.fcw  = (const float*)d_in[20]; p.fcb = (const float*)d_in[21];
  p.out  = (float*)d_out;

  char* ws = (char*)d_ws;
  size_t off = 0;
  p.bar = (int*)(ws + off); off += 1024;     // fenced pre-barrier (global)
  p.flb = (int*)(ws + off); off += 8*64*4;   // octet flag barrier
  p.gf  = (int*)(ws + off); off += 64*16*4;  // per-b group flags (stats sync)
  size_t zero_bytes = off;
  p.sort_ind = (int*)(ws + off); off += 64*4;
  p.dec_len  = (int*)(ws + off); off += 64*4;
  off = (off + 255) & ~(size_t)255;
  p.mnT   = (float*)(ws + off); off += (size_t)B_*512*4;
  p.hfA   = (unsigned*)(ws + off); off += (size_t)B_*256*4;
  p.hfB   = (unsigned*)(ws + off); off += (size_t)B_*256*4;
  p.hfN   = (unsigned*)(ws + off); off += (size_t)B_*256*4;
  p.a2G   = (float*)(ws + off); off += (size_t)B_*512*4;
  p.gateG = (float*)(ws + off); off += (size_t)B_*512*4;
  p.aweQ  = (float*)(ws + off); off += (size_t)B_*4*512*4;
  p.sA    = (float*)(ws + off); off += (size_t)B_*4*2*4;
  off = (off + 255) & ~(size_t)255;
  p.att1  = (float*)(ws + off); off += (size_t)B_*P_*A_*4;

  hipMemsetAsync(ws, 0, zero_bytes, stream);

  void* args[] = { (void*)&p };
  hipLaunchCooperativeKernel((const void*)dec_kernel,
                             dim3(NBLK), dim3(NTHR), args, 0, stream);
}